// Round 3
// baseline (531.400 us; speedup 1.0000x reference)
//
#include <hip/hip_runtime.h>
#include <stdint.h>

#define NNODES 100000
#define NEDGES 100000
#define DIM    256
#define NCH    4          // 2 side + 2 rel
#define ET     64         // edges per block
#define NB     2048       // sort buckets per channel
#define SH     6          // bucket = src >> SH  (64-node windows)

typedef short bf16x8 __attribute__((ext_vector_type(8)));
typedef float f32x4  __attribute__((ext_vector_type(4)));
typedef uint32_t u32x4 __attribute__((ext_vector_type(4)));

__device__ __forceinline__ short f2bf_rn(float x) {
    union { float f; uint32_t u; } v; v.f = x;
    uint32_t u = v.u;
    uint32_t r = u + 0x7fffu + ((u >> 16) & 1u);
    return (short)(r >> 16);
}
__device__ __forceinline__ float bf2f(short s) {
    union { float f; uint32_t u; } v;
    v.u = ((uint32_t)(unsigned short)s) << 16;
    return v.f;
}
__device__ __forceinline__ float asf(uint32_t u) {
    union { float f; uint32_t u; } v; v.u = u; return v.f;
}

// ---------------------------------------------------------------------------
// Counting sort of edges by src bucket (per channel) -> perm[c][i]
// ---------------------------------------------------------------------------
__global__ void hist_kernel(const int* __restrict__ src, uint32_t* __restrict__ hist) {
    int t = blockIdx.x * blockDim.x + threadIdx.x;
    if (t >= NCH * NEDGES) return;
    int c = t / NEDGES;
    uint32_t b = ((uint32_t)src[t]) >> SH;
    atomicAdd(&hist[c * NB + b], 1u);
}

__global__ void scan_kernel(const uint32_t* __restrict__ hist, uint32_t* __restrict__ offs) {
    int w = threadIdx.x >> 6;     // channel (4 waves)
    int lane = threadIdx.x & 63;
    uint32_t running = 0;
    for (int ch = 0; ch < NB / 64; ++ch) {
        uint32_t v = hist[w * NB + ch * 64 + lane];
        uint32_t x = v;
#pragma unroll
        for (int o = 1; o < 64; o <<= 1) {
            uint32_t n = __shfl_up(x, o, 64);
            if (lane >= o) x += n;
        }
        offs[w * NB + ch * 64 + lane] = running + x - v;   // exclusive
        running += __shfl(x, 63, 64);
    }
}

__global__ void scatter_kernel(const int* __restrict__ src, uint32_t* __restrict__ offs,
                               uint32_t* __restrict__ perm) {
    int t = blockIdx.x * blockDim.x + threadIdx.x;
    if (t >= NCH * NEDGES) return;
    int c = t / NEDGES;
    int e = t - c * NEDGES;
    uint32_t b = ((uint32_t)src[t]) >> SH;
    uint32_t pos = atomicAdd(&offs[c * NB + b], 1u);
    perm[(size_t)c * NEDGES + pos] = (uint32_t)e;
}

// ---------------------------------------------------------------------------
// Prep 1: fused/transposed channel matrices in MFMA B-fragment order, split
// hi/lo bf16. idx = (((c*8+kc)*16+ft)*64+lane)*8+j,
// k = kc*32 + (lane>>4)*8 + j, f = ft*16 + (lane&15).
// ---------------------------------------------------------------------------
__global__ void prep_B(const float* __restrict__ RW,
                       const float* __restrict__ dside,
                       const float* __restrict__ Wrel,
                       short* __restrict__ Bh, short* __restrict__ Bl) {
    int t = blockIdx.x * blockDim.x + threadIdx.x;
    if (t >= NCH * 8 * 16 * 64) return;
    int lane = t & 63;
    int ft   = (t >> 6) & 15;
    int kc   = (t >> 10) & 7;
    int c    = t >> 13;
    int quad = lane >> 4, col = lane & 15;
    int f     = ft * 16 + col;
    int kbase = kc * 32 + quad * 8;

    bf16x8 vh, vl;
#pragma unroll
    for (int j = 0; j < 8; ++j) {
        int k = kbase + j;
        float val;
        if (c < 2) {
            val = dside[c * DIM + f] * RW[f * DIM + k] * dside[c * DIM + k];
        } else {
            val = Wrel[(size_t)(c - 2) * DIM * DIM + f * DIM + k];
        }
        short hi = f2bf_rn(val);
        float rem = val - bf2f(hi);
        vh[j] = hi;
        vl[j] = f2bf_rn(rem);
    }
    ((bf16x8*)Bh)[t] = vh;
    ((bf16x8*)Bl)[t] = vl;
}

// ---------------------------------------------------------------------------
// Prep 2: pack h as u32 = (bf16_hi << 16) | bf16_lo, same [node][256] layout.
// ---------------------------------------------------------------------------
__global__ void prep_pack(const float* __restrict__ h, uint32_t* __restrict__ pk) {
    int t = blockIdx.x * blockDim.x + threadIdx.x;
    if (t >= NNODES * DIM / 4) return;
    f32x4 x = ((const f32x4*)h)[t];
    u32x4 o;
#pragma unroll
    for (int j = 0; j < 4; ++j) {
        short hi = f2bf_rn(x[j]);
        short lo = f2bf_rn(x[j] - bf2f(hi));
        o[j] = ((uint32_t)(unsigned short)hi << 16) | (uint32_t)(unsigned short)lo;
    }
    ((u32x4*)pk)[t] = o;
}

// ---------------------------------------------------------------------------
// Fused edge kernel. PACKED: h pre-split as u32(hi<<16|lo). SORTED: edges
// taken through a src-sorted permutation for gather locality.
// Per (channel, 64-edge tile): C(64x256) = U(64x256) @ Mt (3-term split MFMA),
// score[e] = sum_f (C[e][f] + bias[f]) * V[e][f].
// Block = 4 waves; wave w owns f-range [w*64, w*64+64).
// ---------------------------------------------------------------------------
template <bool PACKED, bool SORTED>
__global__ __launch_bounds__(256, 3)
void edge_kernel(const void* __restrict__ hsrc,
                 const int* __restrict__ src_idx,
                 const int* __restrict__ dst_idx,
                 const float* __restrict__ brel,
                 const short* __restrict__ Bh_sw,
                 const short* __restrict__ Bl_sw,
                 const uint32_t* __restrict__ perm,
                 float* __restrict__ out) {
    const int c    = blockIdx.y;
    const int e0   = blockIdx.x * ET;
    const int tid  = threadIdx.x;
    const int w    = tid >> 6;
    const int lane = tid & 63;
    const int quad = lane >> 4, col = lane & 15;

    __shared__ uint32_t s_src[ET];
    __shared__ uint32_t s_dst[ET];
    __shared__ uint32_t s_ge[ET];
    __shared__ float    red[4][ET];

    if (tid < ET) {
        int idx = e0 + tid;
        int ge = 0;
        int si = 0, di = 0;
        if (idx < NEDGES) {
            ge = SORTED ? (int)perm[(size_t)c * NEDGES + idx] : idx;
            si = src_idx[(size_t)c * NEDGES + ge];
            di = dst_idx[(size_t)c * NEDGES + ge];
        }
        s_ge[tid]  = (uint32_t)ge;
        s_src[tid] = (uint32_t)si;
        s_dst[tid] = (uint32_t)di;
    }
    __syncthreads();

    f32x4 acc[4][4];
#pragma unroll
    for (int i = 0; i < 4; ++i)
#pragma unroll
        for (int j = 0; j < 4; ++j) acc[i][j] = (f32x4){0.f, 0.f, 0.f, 0.f};

    const uint32_t* pk = (const uint32_t*)hsrc;
    const float*    hf = (const float*)hsrc;

    // Per-lane A-row bases (A row m = col within each 16-edge m-tile).
    const uint32_t* basep[4];
    const float*    basef[4];
#pragma unroll
    for (int mt = 0; mt < 4; ++mt) {
        size_t off = (size_t)s_src[mt * 16 + col] * DIM;
        if constexpr (PACKED) basep[mt] = pk + off; else basef[mt] = hf + off;
    }

    const bf16x8* Bh = (const bf16x8*)Bh_sw;
    const bf16x8* Bl = (const bf16x8*)Bl_sw;

#pragma unroll
    for (int kc = 0; kc < 8; ++kc) {
        // A fragments: lane holds U[e = mt*16+col][k..k+7] split hi/lo.
        bf16x8 Ah[4], Al[4];
#pragma unroll
        for (int mt = 0; mt < 4; ++mt) {
            bf16x8 ah, al;
            if constexpr (PACKED) {
                const u32x4* p4 = (const u32x4*)(basep[mt] + kc * 32 + quad * 8);
                u32x4 p0 = p4[0];
                u32x4 p1 = p4[1];
#pragma unroll
                for (int j = 0; j < 4; ++j) {
                    ah[j]     = (short)(p0[j] >> 16);
                    al[j]     = (short)(p0[j] & 0xffffu);
                    ah[4 + j] = (short)(p1[j] >> 16);
                    al[4 + j] = (short)(p1[j] & 0xffffu);
                }
            } else {
                const f32x4* p4 = (const f32x4*)(basef[mt] + kc * 32 + quad * 8);
                f32x4 x0 = p4[0];
                f32x4 x1 = p4[1];
#pragma unroll
                for (int j = 0; j < 4; ++j) {
                    short hi = f2bf_rn(x0[j]);
                    ah[j] = hi; al[j] = f2bf_rn(x0[j] - bf2f(hi));
                }
#pragma unroll
                for (int j = 0; j < 4; ++j) {
                    short hi = f2bf_rn(x1[j]);
                    ah[4 + j] = hi; al[4 + j] = f2bf_rn(x1[j] - bf2f(hi));
                }
            }
            Ah[mt] = ah;
            Al[mt] = al;
        }
        // B fragments from pre-swizzled global (L2-resident); 3-term split MFMA.
        int fb = ((c * 8 + kc) * 16 + w * 4) * 64 + lane;
#pragma unroll
        for (int ft = 0; ft < 4; ++ft) {
            bf16x8 bh = Bh[fb + ft * 64];
            bf16x8 bl = Bl[fb + ft * 64];
#pragma unroll
            for (int mt = 0; mt < 4; ++mt) {
                acc[mt][ft] = __builtin_amdgcn_mfma_f32_16x16x32_bf16(Ah[mt], bh, acc[mt][ft], 0, 0, 0);
                acc[mt][ft] = __builtin_amdgcn_mfma_f32_16x16x32_bf16(Ah[mt], bl, acc[mt][ft], 0, 0, 0);
                acc[mt][ft] = __builtin_amdgcn_mfma_f32_16x16x32_bf16(Al[mt], bh, acc[mt][ft], 0, 0, 0);
            }
        }
    }

    // Epilogue: score_e = sum_f (C[e][f] + bias[f]) * V[e][f]
    // C/D layout: row(e) = quad*4 + reg, col(f) = lane&15.
    float bias[4];
#pragma unroll
    for (int ft = 0; ft < 4; ++ft) {
        int f = w * 64 + ft * 16 + col;
        bias[ft] = (c >= 2) ? brel[(size_t)(c - 2) * DIM + f] : 0.f;
    }

    float psum[4][4];  // [mt][r]
#pragma unroll
    for (int mt = 0; mt < 4; ++mt) {
#pragma unroll
        for (int r = 0; r < 4; ++r) {
            int el = mt * 16 + quad * 4 + r;
            size_t roff = (size_t)s_dst[el] * DIM;
            float s = 0.f;
#pragma unroll
            for (int ft = 0; ft < 4; ++ft) {
                int f = w * 64 + ft * 16 + col;
                float v;
                if constexpr (PACKED) {
                    uint32_t u = pk[roff + f];
                    v = asf(u & 0xffff0000u) + asf(u << 16);
                } else {
                    v = hf[roff + f];
                }
                s += (acc[mt][ft][r] + bias[ft]) * v;
            }
            psum[mt][r] = s;
        }
    }

    // Reduce across the 16 f-columns (xor lane bits 0..3)
#pragma unroll
    for (int off = 1; off < 16; off <<= 1) {
#pragma unroll
        for (int mt = 0; mt < 4; ++mt)
#pragma unroll
            for (int r = 0; r < 4; ++r)
                psum[mt][r] += __shfl_xor(psum[mt][r], off, 64);
    }
    if (col == 0) {
#pragma unroll
        for (int mt = 0; mt < 4; ++mt)
#pragma unroll
            for (int r = 0; r < 4; ++r)
                red[w][mt * 16 + quad * 4 + r] = psum[mt][r];
    }
    __syncthreads();

    if (tid < ET) {
        int idx = e0 + tid;
        if (idx < NEDGES) {
            float s = red[0][tid] + red[1][tid] + red[2][tid] + red[3][tid];
            out[(size_t)c * NEDGES + s_ge[tid]] = s;
        }
    }
}

extern "C" void kernel_launch(void* const* d_in, const int* in_sizes, int n_in,
                              void* d_out, int out_size, void* d_ws, size_t ws_size,
                              hipStream_t stream) {
    const float* hmat  = (const float*)d_in[0];
    const int*   src   = (const int*)d_in[1];
    const int*   dst   = (const int*)d_in[2];
    const float* RW    = (const float*)d_in[3];
    const float* dside = (const float*)d_in[4];
    const float* Wrel  = (const float*)d_in[5];
    const float* brel  = (const float*)d_in[6];
    float* out = (float*)d_out;

    // Workspace layout:
    //   Bh (512 KB) | Bl (512 KB) | hist (32 KB) | offs (32 KB) |
    //   perm (1.6 MB) | packed h (102.4 MB)
    const size_t nB      = (size_t)NCH * DIM * DIM;           // shorts per table
    const size_t bTables = 2 * nB * sizeof(short);
    const size_t histB   = (size_t)NCH * NB * sizeof(uint32_t);
    const size_t permB   = (size_t)NCH * NEDGES * sizeof(uint32_t);
    const size_t pkB     = (size_t)NNODES * DIM * sizeof(uint32_t);

    short* Bh = (short*)d_ws;
    short* Bl = Bh + nB;

    prep_B<<<dim3((NCH * 8 * 16 * 64) / 256), dim3(256), 0, stream>>>(RW, dside, Wrel, Bh, Bl);

    dim3 grid((NEDGES + ET - 1) / ET, NCH);
    const int nE = NCH * NEDGES;

    if (ws_size >= bTables + 2 * histB + permB + pkB) {
        // Full path: sorted + packed
        uint32_t* hist = (uint32_t*)((char*)d_ws + bTables);
        uint32_t* offs = hist + (size_t)NCH * NB;
        uint32_t* perm = offs + (size_t)NCH * NB;
        uint32_t* pk   = perm + (size_t)NCH * NEDGES;

        hipMemsetAsync(hist, 0, histB, stream);
        hist_kernel<<<dim3((nE + 255) / 256), dim3(256), 0, stream>>>(src, hist);
        scan_kernel<<<dim3(1), dim3(256), 0, stream>>>(hist, offs);
        scatter_kernel<<<dim3((nE + 255) / 256), dim3(256), 0, stream>>>(src, offs, perm);
        prep_pack<<<dim3((NNODES * DIM / 4 + 255) / 256), dim3(256), 0, stream>>>(hmat, pk);
        edge_kernel<true, true><<<grid, dim3(256), 0, stream>>>(pk, src, dst, brel, Bh, Bl, perm, out);
    } else if (ws_size >= bTables + pkB) {
        uint32_t* pk = (uint32_t*)((char*)d_ws + bTables);
        prep_pack<<<dim3((NNODES * DIM / 4 + 255) / 256), dim3(256), 0, stream>>>(hmat, pk);
        edge_kernel<true, false><<<grid, dim3(256), 0, stream>>>(pk, src, dst, brel, Bh, Bl, nullptr, out);
    } else {
        edge_kernel<false, false><<<grid, dim3(256), 0, stream>>>(hmat, src, dst, brel, Bh, Bl, nullptr, out);
    }
}

// Round 4
// 363.975 us; speedup vs baseline: 1.4600x; 1.4600x over previous
//
#include <hip/hip_runtime.h>
#include <stdint.h>

#define NNODES 100000
#define NEDGES 100000
#define DIM    256
#define NCH    4          // 2 side + 2 rel
#define ET     64         // edges per block

typedef short bf16x8 __attribute__((ext_vector_type(8)));
typedef float f32x4  __attribute__((ext_vector_type(4)));
typedef uint32_t u32x4 __attribute__((ext_vector_type(4)));

__device__ __forceinline__ short f2bf_rn(float x) {
    union { float f; uint32_t u; } v; v.f = x;
    uint32_t u = v.u;
    uint32_t r = u + 0x7fffu + ((u >> 16) & 1u);
    return (short)(r >> 16);
}
__device__ __forceinline__ float bf2f(short s) {
    union { float f; uint32_t u; } v;
    v.u = ((uint32_t)(unsigned short)s) << 16;
    return v.f;
}

// ---------------------------------------------------------------------------
// Prep: fused/transposed channel matrices in MFMA B-fragment order, split
// hi/lo bf16. idx = (((c*8+kc)*16+ft)*64+lane)*8+j,
// k = kc*32 + (lane>>4)*8 + j, f = ft*16 + (lane&15).
//   M_c[f][k] = d_side[c][f]*R_W[f][k]*d_side[c][k]   (c < 2)
//             = W_rel[c-2][f][k]                       (c >= 2)
// ---------------------------------------------------------------------------
__global__ void prep_B(const float* __restrict__ RW,
                       const float* __restrict__ dside,
                       const float* __restrict__ Wrel,
                       short* __restrict__ Bh, short* __restrict__ Bl) {
    int t = blockIdx.x * blockDim.x + threadIdx.x;
    if (t >= NCH * 8 * 16 * 64) return;
    int lane = t & 63;
    int ft   = (t >> 6) & 15;
    int kc   = (t >> 10) & 7;
    int c    = t >> 13;
    int quad = lane >> 4, col = lane & 15;
    int f     = ft * 16 + col;
    int kbase = kc * 32 + quad * 8;

    bf16x8 vh, vl;
#pragma unroll
    for (int j = 0; j < 8; ++j) {
        int k = kbase + j;
        float val;
        if (c < 2) {
            val = dside[c * DIM + f] * RW[f * DIM + k] * dside[c * DIM + k];
        } else {
            val = Wrel[(size_t)(c - 2) * DIM * DIM + f * DIM + k];
        }
        short hi = f2bf_rn(val);
        float rem = val - bf2f(hi);
        vh[j] = hi;
        vl[j] = f2bf_rn(rem);
    }
    ((bf16x8*)Bh)[t] = vh;
    ((bf16x8*)Bl)[t] = vl;
}

// ---------------------------------------------------------------------------
// Fused edge kernel with LDS-staged A fragments.
// Per (channel, 64-edge tile):
//   stage: gathered U rows -> split-bf16 packed u32(hi|lo) A fragments in LDS
//          (each of 64 fragments loaded from global EXACTLY ONCE per block;
//           kills the 4x per-wave redundant scattered gathers = the TA/TCP
//           line-probe bottleneck of rounds 1-3)
//   compute: C(64x256) = U @ Mt via 3-term split-bf16 MFMA, B fragments
//            streamed from the pre-swizzled L2-resident table
//   epilogue: score[e] = sum_f (C[e][f] + bias[f]) * V[e][f], V from f32 h.
// Block = 4 waves; wave w owns f-range [w*64, w*64+64); stages kc {2w,2w+1}.
// ---------------------------------------------------------------------------
#define FRAG_OFF(kc, mt, p) ((((kc) * 8 + (mt) * 2 + (p)) << 10))  // bytes

__global__ __launch_bounds__(256, 2)
void edge_kernel(const float* __restrict__ hmat,
                 const int* __restrict__ src_idx,
                 const int* __restrict__ dst_idx,
                 const float* __restrict__ brel,
                 const short* __restrict__ Bh_sw,
                 const short* __restrict__ Bl_sw,
                 float* __restrict__ out) {
    const int c    = blockIdx.y;
    const int e0   = blockIdx.x * ET;
    const int tid  = threadIdx.x;
    const int w    = tid >> 6;
    const int lane = tid & 63;
    const int quad = lane >> 4, col = lane & 15;

    __shared__ uint32_t s_frag[64 * 256];   // 64 KB: 64 frags x 64 lanes x 16 B
    __shared__ uint32_t s_src[ET];
    __shared__ uint32_t s_dst[ET];
    __shared__ float    red[4][ET];

    if (tid < ET) {
        int idx = e0 + tid;
        int si = 0, di = 0;
        if (idx < NEDGES) {
            si = src_idx[(size_t)c * NEDGES + idx];
            di = dst_idx[(size_t)c * NEDGES + idx];
        }
        s_src[tid] = (uint32_t)si;
        s_dst[tid] = (uint32_t)di;
    }
    __syncthreads();

    // ---- Stage A fragments (wave w: kc = 2w, 2w+1; 16 frags of 1 KB) ----
    // Fragment (kc,mt,p): lane(quad,col) holds u32-packed split of
    // h[src[mt*16+col]][kc*32 + quad*8 + p*4 .. +4].
    {
        const float* rbase[4];
#pragma unroll
        for (int mt = 0; mt < 4; ++mt)
            rbase[mt] = hmat + (size_t)s_src[mt * 16 + col] * DIM;

#pragma unroll
        for (int i = 0; i < 16; ++i) {
            int kc = 2 * w + (i >> 3);
            int mt = (i >> 1) & 3;
            int p  = i & 1;
            f32x4 x = *(const f32x4*)(rbase[mt] + kc * 32 + quad * 8 + p * 4);
            u32x4 o;
#pragma unroll
            for (int j = 0; j < 4; ++j) {
                short hi = f2bf_rn(x[j]);
                short lo = f2bf_rn(x[j] - bf2f(hi));
                o[j] = ((uint32_t)(unsigned short)hi << 16) | (uint32_t)(unsigned short)lo;
            }
            *(u32x4*)((char*)s_frag + FRAG_OFF(kc, mt, p) + lane * 16) = o;
        }
    }
    __syncthreads();

    // ---- K-loop: A from LDS, B from global (L2-resident), split MFMA ----
    f32x4 acc[4][4];
#pragma unroll
    for (int i = 0; i < 4; ++i)
#pragma unroll
        for (int j = 0; j < 4; ++j) acc[i][j] = (f32x4){0.f, 0.f, 0.f, 0.f};

    const bf16x8* Bh = (const bf16x8*)Bh_sw;
    const bf16x8* Bl = (const bf16x8*)Bl_sw;

#pragma unroll
    for (int kc = 0; kc < 8; ++kc) {
        bf16x8 Ah[4], Al[4];
#pragma unroll
        for (int mt = 0; mt < 4; ++mt) {
            u32x4 q0 = *(const u32x4*)((char*)s_frag + FRAG_OFF(kc, mt, 0) + lane * 16);
            u32x4 q1 = *(const u32x4*)((char*)s_frag + FRAG_OFF(kc, mt, 1) + lane * 16);
            bf16x8 ah, al;
#pragma unroll
            for (int j = 0; j < 4; ++j) {
                ah[j]     = (short)(q0[j] >> 16);
                al[j]     = (short)(q0[j] & 0xffffu);
                ah[4 + j] = (short)(q1[j] >> 16);
                al[4 + j] = (short)(q1[j] & 0xffffu);
            }
            Ah[mt] = ah;
            Al[mt] = al;
        }
        int fb = ((c * 8 + kc) * 16 + w * 4) * 64 + lane;
#pragma unroll
        for (int ft = 0; ft < 4; ++ft) {
            bf16x8 bh = Bh[fb + ft * 64];
            bf16x8 bl = Bl[fb + ft * 64];
#pragma unroll
            for (int mt = 0; mt < 4; ++mt) {
                acc[mt][ft] = __builtin_amdgcn_mfma_f32_16x16x32_bf16(Ah[mt], bh, acc[mt][ft], 0, 0, 0);
                acc[mt][ft] = __builtin_amdgcn_mfma_f32_16x16x32_bf16(Ah[mt], bl, acc[mt][ft], 0, 0, 0);
                acc[mt][ft] = __builtin_amdgcn_mfma_f32_16x16x32_bf16(Al[mt], bh, acc[mt][ft], 0, 0, 0);
            }
        }
    }

    // ---- Epilogue: score_e = sum_f (C[e][f] + bias[f]) * V[e][f] ----
    // C/D layout: row(e) = quad*4 + reg, col(f) = lane&15. V read as exact f32.
    float bias[4];
#pragma unroll
    for (int ft = 0; ft < 4; ++ft) {
        int f = w * 64 + ft * 16 + col;
        bias[ft] = (c >= 2) ? brel[(size_t)(c - 2) * DIM + f] : 0.f;
    }

    float psum[4][4];  // [mt][r]
#pragma unroll
    for (int mt = 0; mt < 4; ++mt) {
#pragma unroll
        for (int r = 0; r < 4; ++r) {
            int el = mt * 16 + quad * 4 + r;
            size_t roff = (size_t)s_dst[el] * DIM;
            float s = 0.f;
#pragma unroll
            for (int ft = 0; ft < 4; ++ft) {
                int f = w * 64 + ft * 16 + col;
                float v = hmat[roff + f];
                s += (acc[mt][ft][r] + bias[ft]) * v;
            }
            psum[mt][r] = s;
        }
    }

    // Reduce across the 16 f-columns (xor lane bits 0..3)
#pragma unroll
    for (int off = 1; off < 16; off <<= 1) {
#pragma unroll
        for (int mt = 0; mt < 4; ++mt)
#pragma unroll
            for (int r = 0; r < 4; ++r)
                psum[mt][r] += __shfl_xor(psum[mt][r], off, 64);
    }
    if (col == 0) {
#pragma unroll
        for (int mt = 0; mt < 4; ++mt)
#pragma unroll
            for (int r = 0; r < 4; ++r)
                red[w][mt * 16 + quad * 4 + r] = psum[mt][r];
    }
    __syncthreads();

    if (tid < ET) {
        int idx = e0 + tid;
        if (idx < NEDGES) {
            float s = red[0][tid] + red[1][tid] + red[2][tid] + red[3][tid];
            out[(size_t)c * NEDGES + idx] = s;
        }
    }
}

extern "C" void kernel_launch(void* const* d_in, const int* in_sizes, int n_in,
                              void* d_out, int out_size, void* d_ws, size_t ws_size,
                              hipStream_t stream) {
    const float* hmat  = (const float*)d_in[0];
    const int*   src   = (const int*)d_in[1];
    const int*   dst   = (const int*)d_in[2];
    const float* RW    = (const float*)d_in[3];
    const float* dside = (const float*)d_in[4];
    const float* Wrel  = (const float*)d_in[5];
    const float* brel  = (const float*)d_in[6];
    float* out = (float*)d_out;

    // Workspace: Bh (512 KB) | Bl (512 KB)
    const size_t nB = (size_t)NCH * DIM * DIM;   // shorts per table
    short* Bh = (short*)d_ws;
    short* Bl = Bh + nB;

    prep_B<<<dim3((NCH * 8 * 16 * 64) / 256), dim3(256), 0, stream>>>(RW, dside, Wrel, Bh, Bl);

    dim3 grid((NEDGES + ET - 1) / ET, NCH);
    edge_kernel<<<grid, dim3(256), 0, stream>>>(hmat, src, dst, brel, Bh, Bl, out);
}